// Round 18
// baseline (6204.968 us; speedup 1.0000x reference)
//
#include <hip/hip_runtime.h>
#include <stdint.h>

typedef short bf16x8 __attribute__((ext_vector_type(8)));
typedef short s16x4 __attribute__((ext_vector_type(4)));
typedef float f32x4 __attribute__((ext_vector_type(4)));
typedef unsigned int u32;
typedef unsigned short u16;
typedef unsigned long long u64;

// ---------------- workspace layout (bytes) ----------------
#define OFF_WXT  0ull                  // [2][3][1536][1024] bf16  (Wx transposed)
#define OFF_WHF  18874368ull           // [3][2][32][3][16][64][8] bf16 (Wh frags)
#define OFF_CTR  28311552ull           // [8 groups][16 producers] flag lines (128B)
#define OFF_PRJT 37748736ull           // [3][1024][1024] bf16 (proj_W^T)
#define OFF_IPJT 44040192ull           // [1024][1024] bf16 (in_proj_W^T)
#define OFF_XB   46137344ull           // [32768][1024] bf16 (activations)
#define OFF_G    113246208ull          // [2][512*96*4][256] bf16 (gate-x frags)
#define OFF_OCAT 314572800ull          // [32768][1024] bf16 (hf|hb)
#define OFF_INP  381681664ull          // [32768][1024] f32 (highway inputs)
#define OFF_HB   515899392ull          // [2][2][64][512] bf16 (h double-buf)
#define WS_NEED  516161536ull

__device__ __forceinline__ float b2f(u32 u){ return __uint_as_float(u<<16); }
__device__ __forceinline__ u16 f2b(float f){
  u32 i = __float_as_uint(f);
  return (u16)((i + 0x7FFFu + ((i>>16)&1u))>>16);
}
__device__ __forceinline__ float sigm(float x){ return 1.f/(1.f+__expf(-x)); }
__device__ __forceinline__ float tanh_f(float x){
  x = fminf(fmaxf(x,-15.f),15.f);
  float e = __expf(2.f*x);
  return (e-1.f)/(e+1.f);
}
__device__ __forceinline__ void gl_lds16(const void* g, void* l){
  __builtin_amdgcn_global_load_lds((const __attribute__((address_space(1))) u32*)g,
                                   (__attribute__((address_space(3))) u32*)l, 16, 0, 0);
}

// ---------------- prep kernels (coalesced) ----------------
__global__ void k_convx(const float4* __restrict__ x, u64* __restrict__ xb){
  long i = (long)blockIdx.x*blockDim.x + threadIdx.x;   // 8388608 threads
  float4 v = x[i];
  xb[i] = (u64)f2b(v.x) | ((u64)f2b(v.y)<<16) | ((u64)f2b(v.z)<<32) | ((u64)f2b(v.w)<<48);
}

// generic 64x64 LDS-tiled transpose f32 -> bf16 for WXT / PRJT / IPJT
__global__ __launch_bounds__(256)
void k_tr(const float* __restrict__ fw, const float* __restrict__ bw,
          const float* __restrict__ pw, const float* __restrict__ ipw,
          u16* __restrict__ wxt, u16* __restrict__ pjt, u16* __restrict__ ipjt){
  __shared__ u16 lds[64][66];
  const int b = blockIdx.x;                 // 3328 total
  const float* src; u16* dst; int srcLD, dstLD, r0, c0;
  if (b < 2304){                            // WXT: 6 mats x (16 k-tiles x 24 n-tiles)
    int mat = b / 384, tt = b % 384;
    int kt = tt % 16, nt = tt / 16;
    int d = mat / 3, l = mat % 3;
    src = (d ? bw : fw) + (size_t)l*1536*1536; srcLD = 1536;
    dst = wxt + (size_t)mat*1536*1024;        dstLD = 1024;
    r0 = kt*64; c0 = nt*64;
  } else if (b < 3072){                     // PRJT: 3 x (16x16)
    int bb = b - 2304, mat = bb / 256, tt = bb % 256;
    int kt = tt % 16, nt = tt / 16;
    src = pw + (size_t)mat*1048576; srcLD = 1024;
    dst = pjt + (size_t)mat*1048576; dstLD = 1024;
    r0 = kt*64; c0 = nt*64;
  } else {                                  // IPJT: 16x16
    int tt = b - 3072;
    int kt = tt % 16, nt = tt / 16;
    src = ipw; srcLD = 1024; dst = ipjt; dstLD = 1024;
    r0 = kt*64; c0 = nt*64;
  }
  const int tr = threadIdx.x >> 6, tc = threadIdx.x & 63;
  #pragma unroll
  for (int i=0;i<16;i++){
    int r = i*4 + tr;
    lds[r][tc] = f2b(src[(size_t)(r0+r)*srcLD + c0 + tc]);
  }
  __syncthreads();
  #pragma unroll
  for (int i=0;i<16;i++){
    int nr = i*4 + tr;
    dst[(size_t)(c0+nr)*dstLD + r0 + tc] = lds[tc][nr];
  }
}

// Wh fragment pack, coalesced reads via LDS tile
__global__ __launch_bounds__(256)
void k_whf2(const float* __restrict__ fw, const float* __restrict__ bw, u16* __restrict__ out){
  __shared__ u16 lds[64][66];
  const int b = blockIdx.x;                 // 1152 = 6 mats x (8 r-tiles x 24 c-tiles)
  const int mat = b / 192, tt = b % 192;
  const int rt = tt & 7, ct = tt >> 3;
  const int l = mat >> 1, d = mat & 1;
  const float* W = (d ? bw : fw) + (size_t)l*1536*1536;
  const int tr = threadIdx.x >> 6, tc = threadIdx.x & 63;
  #pragma unroll
  for (int i=0;i<16;i++){
    int r = i*4 + tr;
    lds[r][tc] = f2b(W[(size_t)(1024 + rt*64 + r)*1536 + ct*64 + tc]);
  }
  __syncthreads();
  const int t = threadIdx.x;
  const int lane = t >> 2;
  const int e0 = (t & 3)*2;
  u32* o32 = (u32*)out;
  #pragma unroll
  for (int kkl=0; kkl<2; ++kkl){
    int rl = kkl*32 + (lane>>4)*8 + e0;
    int kk = rt*2 + kkl;
    #pragma unroll
    for (int cg=0; cg<4; ++cg){
      int col = ct*64 + cg*16;
      int g = col >> 9;
      int wg = (col & 511) >> 4;
      size_t base16 = (size_t)l*1572864 + (size_t)((d*32+wg)*3 + g)*8192 + (size_t)kk*512;
      u16 lo = lds[rl    ][cg*16 + (lane&15)];
      u16 hi = lds[rl + 1][cg*16 + (lane&15)];
      o32[base16/2 + t] = (u32)lo | ((u32)hi<<16);
    }
  }
}

// ---------------- FUSED fw+bw gate GEMM: A staged once, used twice ----------------
// ROUND 18: fw and bw gate GEMMs read the IDENTICAL A (XB). One launch computes
// both: per (mblk,nblk) tile stage A + B_fw + B_bw panels, 2x MFMA per A elem.
// Halves A HBM traffic by construction (round-11: FETCH=418MB vs ~70 ideal).
__global__ __launch_bounds__(256, 1)
void gemm_gates(const u16* __restrict__ A, const u16* __restrict__ Btf,
                const u16* __restrict__ Btb,
                const float* __restrict__ biasf, const float* __restrict__ biasb,
                u16* __restrict__ Gout)
{
  __shared__ u16 As[128*64];
  __shared__ u16 Bfs[128*64];
  __shared__ u16 Bbs[128*64];
  const int tid = threadIdx.x, wid = tid>>6, lane = tid&63;
  const int wr = wid>>1, wc = wid&1;
  const int mblk = blockIdx.x & 255;
  const int nblk = blockIdx.x >> 8;          // 0..11
  f32x4 accf[4][4], accb[4][4];
  #pragma unroll
  for (int i=0;i<4;i++)
    #pragma unroll
    for (int j=0;j<4;j++){ accf[i][j] = (f32x4){0.f,0.f,0.f,0.f}; accb[i][j] = (f32x4){0.f,0.f,0.f,0.f}; }
  const size_t Kb = 2048;                    // K=1024 bf16
  const char* Ab  = (const char*)A   + (size_t)(mblk*128)*Kb;
  const char* Bfb = (const char*)Btf + (size_t)(nblk*128)*Kb;
  const char* Bbb = (const char*)Btb + (size_t)(nblk*128)*Kb;
  const int r8 = lane>>3, c8 = lane&7;
  for (int kt=0; kt<16; ++kt){
    __syncthreads();
    #pragma unroll
    for (int i=0;i<4;i++){
      const int instr = wid*4 + i;
      const int row = instr*8 + r8;
      const int so = (c8*16) ^ ((row&7)<<4);          // T2 swizzle via pre-swizzled src
      gl_lds16(Ab  + (size_t)row*Kb + kt*128 + so, (char*)As  + instr*1024);
      gl_lds16(Bfb + (size_t)row*Kb + kt*128 + so, (char*)Bfs + instr*1024);
      gl_lds16(Bbb + (size_t)row*Kb + kt*128 + so, (char*)Bbs + instr*1024);
    }
    __syncthreads();
    #pragma unroll
    for (int ks=0; ks<2; ++ks){
      bf16x8 af[4], bf_[4], bb_[4];
      #pragma unroll
      for (int mt=0;mt<4;mt++){
        int r = wr*64 + mt*16 + (lane&15);
        int kb = (ks*64 + ((lane>>4)*16)) ^ ((r&7)<<4);
        af[mt] = *(const bf16x8*)((const char*)As + r*128 + kb);
      }
      #pragma unroll
      for (int nt=0;nt<4;nt++){
        int r = wc*64 + nt*16 + (lane&15);
        int kb = (ks*64 + ((lane>>4)*16)) ^ ((r&7)<<4);
        bf_[nt] = *(const bf16x8*)((const char*)Bfs + r*128 + kb);
        bb_[nt] = *(const bf16x8*)((const char*)Bbs + r*128 + kb);
      }
      #pragma unroll
      for (int mt=0;mt<4;mt++)
        #pragma unroll
        for (int nt=0;nt<4;nt++){
          accf[mt][nt] = __builtin_amdgcn_mfma_f32_16x16x32_bf16(af[mt], bf_[nt], accf[mt][nt], 0,0,0);
          accb[mt][nt] = __builtin_amdgcn_mfma_f32_16x16x32_bf16(af[mt], bb_[nt], accb[mt][nt], 0,0,0);
        }
    }
  }
  const int mb = mblk*128 + wr*64;
  const int nb = nblk*128 + wc*64;
  #pragma unroll
  for (int nt=0;nt<4;nt++){
    const int n = nb + nt*16 + (lane&15);
    const float bvf = biasf[n];
    const float bvb = biasb[n];
    #pragma unroll
    for (int mt=0;mt<4;mt++){
      #pragma unroll
      for (int r=0;r<4;r++){
        const int m = mb + mt*16 + (lane>>4)*4 + r;
        int b = m >> 9, t = m & 511;
        int brow = b & 15;
        size_t col = (size_t)((n>>9)*32 + ((n&511)>>4));
        size_t sub = (size_t)((brow>>2)<<6) + ((n&15)<<2) + (brow&3);
        size_t idf = (((size_t)t*96 + col)*4 + (b>>4))*256 + sub;
        size_t idb = (((size_t)(511-t)*96 + col)*4 + (b>>4))*256 + sub;
        Gout[idf] = f2b(accf[mt][nt][r] + bvf);
        Gout[50331648ull + idb] = f2b(accb[mt][nt][r] + bvb);
      }
    }
  }
}

// ---------------- tiled bf16 MFMA GEMM (B^T input), fused epilogues ----------------
// round-8 exact (mblk-fastest mapping, plain stores). V==1 in_proj, V==2 proj.
template<int V>
__global__ __launch_bounds__(256)
void gemm_bt(const u16* __restrict__ A, const u16* __restrict__ Bt,
             const float* __restrict__ bias, int K,
             u16* __restrict__ Gout, int dir,
             float* __restrict__ inputs,
             const u16* __restrict__ ocat, u16* __restrict__ xbout,
             float* __restrict__ dout)
{
  __shared__ u16 As[128*64];
  __shared__ u16 Bs[128*64];
  const int tid = threadIdx.x, wid = tid>>6, lane = tid&63;
  const int wr = wid>>1, wc = wid&1;
  const int mblk = blockIdx.x & 255;
  const int nblk = blockIdx.x >> 8;
  f32x4 acc[4][4];
  #pragma unroll
  for (int i=0;i<4;i++)
    #pragma unroll
    for (int j=0;j<4;j++) acc[i][j] = (f32x4){0.f,0.f,0.f,0.f};
  const size_t Kb = (size_t)K*2;
  const char* Ab = (const char*)A + (size_t)(mblk*128)*Kb;
  const char* Bb = (const char*)Bt + (size_t)(nblk*128)*Kb;
  const int r8 = lane>>3, c8 = lane&7;
  for (int kt=0; kt<K/64; ++kt){
    __syncthreads();
    #pragma unroll
    for (int i=0;i<4;i++){
      const int instr = wid*4 + i;
      const int row = instr*8 + r8;
      const int so = (c8*16) ^ ((row&7)<<4);          // T2 swizzle via pre-swizzled src
      gl_lds16(Ab + (size_t)row*Kb + kt*128 + so, (char*)As + instr*1024);
      gl_lds16(Bb + (size_t)row*Kb + kt*128 + so, (char*)Bs + instr*1024);
    }
    __syncthreads();
    #pragma unroll
    for (int ks=0; ks<2; ++ks){
      bf16x8 af[4], bfv[4];
      #pragma unroll
      for (int mt=0;mt<4;mt++){
        int r = wr*64 + mt*16 + (lane&15);
        int kb = (ks*64 + ((lane>>4)*16)) ^ ((r&7)<<4);
        af[mt] = *(const bf16x8*)((const char*)As + r*128 + kb);
      }
      #pragma unroll
      for (int nt=0;nt<4;nt++){
        int r = wc*64 + nt*16 + (lane&15);
        int kb = (ks*64 + ((lane>>4)*16)) ^ ((r&7)<<4);
        bfv[nt] = *(const bf16x8*)((const char*)Bs + r*128 + kb);
      }
      #pragma unroll
      for (int mt=0;mt<4;mt++)
        #pragma unroll
        for (int nt=0;nt<4;nt++)
          acc[mt][nt] = __builtin_amdgcn_mfma_f32_16x16x32_bf16(af[mt], bfv[nt], acc[mt][nt], 0,0,0);
    }
  }
  const int mb = mblk*128 + wr*64;
  const int nb = nblk*128 + wc*64;
  #pragma unroll
  for (int nt=0;nt<4;nt++){
    const int n = nb + nt*16 + (lane&15);
    const float bv = bias[n];
    #pragma unroll
    for (int mt=0;mt<4;mt++){
      #pragma unroll
      for (int r=0;r<4;r++){
        const int m = mb + mt*16 + (lane>>4)*4 + r;
        float v = acc[mt][nt][r] + bv;
        if (V==1){
          inputs[(size_t)m*1024 + n] = v;
        } else {
          float g = sigm(v);
          size_t a = (size_t)m*1024 + n;
          float o = b2f((u32)ocat[a]);
          float nv = g*o + (1.f-g)*inputs[a];
          if (dout) dout[a] = nv;
          else { inputs[a] = nv; xbout[a] = f2b(nv); }
        }
      }
    }
  }
}

// ---------------- persistent recurrent kernel (round-17: combined poll) ----------
__global__ __launch_bounds__(512, 1)
void lstm_rec(const u16* __restrict__ Whf, const u16* __restrict__ G,
              u16* __restrict__ hb,
              const float* __restrict__ h0f_, const float* __restrict__ c0f_,
              const float* __restrict__ h0b_, const float* __restrict__ c0b_,
              u16* __restrict__ ocat, u32* __restrict__ ctr, int lay)
{
  const int blk = blockIdx.x;
  const int d  = blk >> 6;
  const int bi = (blk >> 4) & 3;
  const int ci = blk & 15;
  const int tid = threadIdx.x;
  const int wave = tid >> 6, lane = tid & 63;

  __shared__ u16 hlds[16*544];          // logical [16][512], row stride 1088B, XOR-swz
  __shared__ float ldsg[3][16][37];
  __shared__ float ldsc[16][37];

  const int g = wave >> 1, half = wave & 1;
  const bool isg = (wave < 6);

  bf16x8 w[16];
  if (isg){
    const int wgg = ci*2 + half;
    const u16* wb = Whf + (((size_t)(d*32+wgg)*3 + g)*1024 + (size_t)lane)*8;
    #pragma unroll
    for (int kk=0;kk<16;kk++) w[kk] = *(const bf16x8*)(wb + kk*512);
  }
  const float* h0 = d ? h0b_ : h0f_;
  const float* c0 = d ? c0b_ : c0f_;
  u16* hbd = hb + (size_t)d*65536;                    // [2 parity][64][512] bf16
  const u16* Gd = G + (size_t)d*50331648ull;
  u32* av = ctr + (size_t)(d*4+bi)*512;               // group: 16 slots x 32 u32
  const u32 labase = (u32)lay * 513u;

  // init h(0) slice + c0
  if (tid < 256){
    int b = tid >> 4, c2 = (tid & 15)*2;
    int col = ci*32 + c2;
    u32 pk = (u32)f2b(h0[col]) | ((u32)f2b(h0[col+1])<<16);
    __hip_atomic_store((u32*)(hbd + (size_t)(bi*16+b)*512 + col), pk,
                       __ATOMIC_RELAXED, __HIP_MEMORY_SCOPE_AGENT);
    ldsc[b][c2]   = c0[col];
    ldsc[b][c2+1] = c0[col+1];
  }
  __syncthreads();                       // drains init stores
  if (tid==0)
    __hip_atomic_store(av + ci*32, labase + 1u, __ATOMIC_RELAXED, __HIP_MEMORY_SCOPE_AGENT);

  const int ntile = g*32 + ci*2 + half;
  s16x4 q{};
  if (isg)
    q = *(const s16x4*)(Gd + (((size_t)0*96 + ntile)*4 + bi)*256 + lane*4);

  const int srow = lane >> 2;            // staging: row 0..15
  const int part = lane & 3;             // 16B chunk within a producer slice
  const int p0 = wave*2, p1 = wave*2 + 1;
  const int swzw = (srow & 7) << 4;
  char* hlrow = (char*)hlds + srow*1088;
  const int mr = lane & 15;              // MFMA A row
  const char* ab = (const char*)hlds + mr*1088;
  const int c16 = (lane>>4)*16;
  const int swzr = (mr & 7) << 4;

  for (int t=0; t<512; ++t){
    // ---- combined parallel poll of both producers, barrier, THEN stage ----
    const u32 tgt = labase + (u32)t + 1u;
    const u64* hsrc = (const u64*)(hbd + (size_t)(t&1)*32768) + (size_t)bi*2048;
    for (;;){
      u32 fa = __hip_atomic_load(av + p0*32, __ATOMIC_RELAXED, __HIP_MEMORY_SCOPE_AGENT);
      u32 fb = __hip_atomic_load(av + p1*32, __ATOMIC_RELAXED, __HIP_MEMORY_SCOPE_AGENT);
      if (fa >= tgt && fb >= tgt) break;
    }
    asm volatile("" ::: "memory");      // forbid hoisting the slice loads above the polls
    u64 a0 = __hip_atomic_load(hsrc + srow*128 + p0*8 + part*2,     __ATOMIC_RELAXED, __HIP_MEMORY_SCOPE_AGENT);
    u64 a1 = __hip_atomic_load(hsrc + srow*128 + p0*8 + part*2 + 1, __ATOMIC_RELAXED, __HIP_MEMORY_SCOPE_AGENT);
    u64 b0 = __hip_atomic_load(hsrc + srow*128 + p1*8 + part*2,     __ATOMIC_RELAXED, __HIP_MEMORY_SCOPE_AGENT);
    u64 b1 = __hip_atomic_load(hsrc + srow*128 + p1*8 + part*2 + 1, __ATOMIC_RELAXED, __HIP_MEMORY_SCOPE_AGENT);
    *(u64*)(hlrow + ((p0*64 + part*16) ^ swzw))     = a0;
    *(u64*)(hlrow + ((p0*64 + part*16) ^ swzw) + 8) = a1;
    *(u64*)(hlrow + ((p1*64 + part*16) ^ swzw))     = b0;
    *(u64*)(hlrow + ((p1*64 + part*16) ^ swzw) + 8) = b1;
    __syncthreads();

    if (isg){
      f32x4 ea={0.f,0.f,0.f,0.f}, eb={0.f,0.f,0.f,0.f};
      #pragma unroll
      for (int kk=0;kk<16;kk+=2){
        bf16x8 a0v = *(const bf16x8*)(ab + ((kk*64     + c16) ^ swzr));
        bf16x8 a1v = *(const bf16x8*)(ab + ((kk*64+64  + c16) ^ swzr));
        ea = __builtin_amdgcn_mfma_f32_16x16x32_bf16(a0v, w[kk],   ea, 0,0,0);
        eb = __builtin_amdgcn_mfma_f32_16x16x32_bf16(a1v, w[kk+1], eb, 0,0,0);
      }
      const int bb = (lane>>4)*4;
      const int cc = half*16 + (lane&15);
      #pragma unroll
      for (int r=0;r<4;r++)
        ldsg[g][bb+r][cc] = ea[r] + eb[r] + b2f((u32)(u16)q[r]);
    }
    __syncthreads();

    // ---- cell update + write h(t+1) (agent), ocat (plain) ----
    const int t_o = d ? (511 - t) : t;
    u16* hnxt = hbd + (size_t)((t+1)&1)*32768;
    if (tid < 256){
      int b = tid>>4, c2 = (tid&15)*2;
      float i0 = sigm(ldsg[0][b][c2]);
      float i1 = sigm(ldsg[0][b][c2+1]);
      float cn0 = (1.f-i0)*ldsc[b][c2]   + i0*tanh_f(ldsg[1][b][c2]);
      float cn1 = (1.f-i1)*ldsc[b][c2+1] + i1*tanh_f(ldsg[1][b][c2+1]);
      ldsc[b][c2] = cn0; ldsc[b][c2+1] = cn1;
      float hv0 = tanh_f(cn0)*sigm(ldsg[2][b][c2]);
      float hv1 = tanh_f(cn1)*sigm(ldsg[2][b][c2+1]);
      u32 pk = (u32)f2b(hv0) | ((u32)f2b(hv1)<<16);
      int gb = bi*16 + b, col = ci*32 + c2;
      __hip_atomic_store((u32*)(hnxt + (size_t)gb*512 + col), pk,
                         __ATOMIC_RELAXED, __HIP_MEMORY_SCOPE_AGENT);
      *(u32*)(ocat + (((size_t)(gb*512 + t_o))<<10) + (d<<9) + col) = pk;
    }
    __syncthreads();                     // all stores drained (per-wave vmcnt + barrier)

    if (tid==0)
      __hip_atomic_store(av + ci*32, labase + (u32)t + 2u,
                         __ATOMIC_RELAXED, __HIP_MEMORY_SCOPE_AGENT);
    if (isg){
      int tn = (t+1 < 512) ? (t+1) : 511;
      q = *(const s16x4*)(Gd + (((size_t)tn*96 + ntile)*4 + bi)*256 + lane*4);
    }
  }
}

extern "C" void kernel_launch(void* const* d_in, const int* in_sizes, int n_in,
                              void* d_out, int out_size, void* d_ws, size_t ws_size,
                              hipStream_t stream)
{
  (void)in_sizes; (void)n_in; (void)out_size;
  if (ws_size < WS_NEED) return;
  const float* x      = (const float*)d_in[0];
  const float* fw_W   = (const float*)d_in[1];
  const float* fw_b   = (const float*)d_in[2];
  const float* bw_W   = (const float*)d_in[3];
  const float* bw_b   = (const float*)d_in[4];
  const float* h0f    = (const float*)d_in[5];
  const float* c0f    = (const float*)d_in[6];
  const float* h0b    = (const float*)d_in[7];
  const float* c0b    = (const float*)d_in[8];
  const float* proj_W = (const float*)d_in[9];
  const float* proj_b = (const float*)d_in[10];
  const float* ipW    = (const float*)d_in[11];
  const float* ipb    = (const float*)d_in[12];
  char* ws = (char*)d_ws;
  u16* WXT  = (u16*)(ws + OFF_WXT);
  u16* WHF  = (u16*)(ws + OFF_WHF);
  u16* PRJT = (u16*)(ws + OFF_PRJT);
  u16* IPJT = (u16*)(ws + OFF_IPJT);
  u16* XB   = (u16*)(ws + OFF_XB);
  u16* GB   = (u16*)(ws + OFF_G);
  u16* OCAT = (u16*)(ws + OFF_OCAT);
  float* INP= (float*)(ws + OFF_INP);
  u16* HB   = (u16*)(ws + OFF_HB);
  u32* CTR  = (u32*)(ws + OFF_CTR);

  hipMemsetAsync(CTR, 0, 16384, stream);
  k_convx<<<32768, 256, 0, stream>>>((const float4*)x, (u64*)XB);
  k_tr<<<3328, 256, 0, stream>>>(fw_W, bw_W, proj_W, ipW, WXT, PRJT, IPJT);
  k_whf2<<<1152, 256, 0, stream>>>(fw_W, bw_W, WHF);

  gemm_bt<1><<<2048, 256, 0, stream>>>(XB, IPJT, ipb, 1024, nullptr, 0, INP, nullptr, nullptr, nullptr);

  for (int l=0; l<3; ++l){
    gemm_gates<<<3072, 256, 0, stream>>>(XB, WXT + (size_t)l*1572864,
                                         WXT + (size_t)(3+l)*1572864,
                                         fw_b + l*1536, bw_b + l*1536, GB);
    {
      const u16* whfl = WHF + (size_t)l*1572864;
      const u16* gbp  = GB;
      u16* hbp = HB;
      const float* p1 = h0f + l*512;
      const float* p2 = c0f + l*512;
      const float* p3 = h0b + l*512;
      const float* p4 = c0b + l*512;
      u16* ocp = OCAT;
      u32* ctp = CTR;
      int lay = l;
      void* args[] = { (void*)&whfl, (void*)&gbp, (void*)&hbp,
                       (void*)&p1, (void*)&p2, (void*)&p3, (void*)&p4,
                       (void*)&ocp, (void*)&ctp, (void*)&lay };
      hipLaunchCooperativeKernel((void*)lstm_rec, dim3(128), dim3(512), args, 0, stream);
    }
    gemm_bt<2><<<2048, 256, 0, stream>>>(OCAT, PRJT + (size_t)l*1048576, proj_b + l*1024, 1024,
                                         nullptr, 0, INP, OCAT, XB,
                                         (l==2) ? (float*)d_out : nullptr);
  }
}

// Round 19
// 5857.565 us; speedup vs baseline: 1.0593x; 1.0593x over previous
//
#include <hip/hip_runtime.h>
#include <stdint.h>

typedef short bf16x8 __attribute__((ext_vector_type(8)));
typedef short s16x4 __attribute__((ext_vector_type(4)));
typedef float f32x4 __attribute__((ext_vector_type(4)));
typedef unsigned int u32;
typedef unsigned short u16;
typedef unsigned long long u64;

// ---------------- workspace layout (bytes) ----------------
#define OFF_WXT  0ull                  // [2][3][1536][1024] bf16  (Wx transposed)
#define OFF_WHF  18874368ull           // [3][2][32][3][16][64][8] bf16 (Wh frags)
#define OFF_CTR  28311552ull           // [8 groups][16 producers] flag lines (128B)
#define OFF_PRJT 37748736ull           // [3][1024][1024] bf16 (proj_W^T)
#define OFF_IPJT 44040192ull           // [1024][1024] bf16 (in_proj_W^T)
#define OFF_XB   46137344ull           // [32768][1024] bf16 (activations)
#define OFF_G    113246208ull          // [2][512*96*4][256] bf16 (gate-x frags)
#define OFF_OCAT 314572800ull          // [32768][1024] bf16 (hf|hb)
#define OFF_INP  381681664ull          // [32768][1024] f32 (highway inputs)
#define OFF_HB   515899392ull          // [2][2][64][512] bf16 (h double-buf)
#define WS_NEED  516161536ull

__device__ __forceinline__ float b2f(u32 u){ return __uint_as_float(u<<16); }
__device__ __forceinline__ u16 f2b(float f){
  u32 i = __float_as_uint(f);
  return (u16)((i + 0x7FFFu + ((i>>16)&1u))>>16);
}
__device__ __forceinline__ float sigm(float x){ return 1.f/(1.f+__expf(-x)); }
__device__ __forceinline__ float tanh_f(float x){
  x = fminf(fmaxf(x,-15.f),15.f);
  float e = __expf(2.f*x);
  return (e-1.f)/(e+1.f);
}
__device__ __forceinline__ void gl_lds16(const void* g, void* l){
  __builtin_amdgcn_global_load_lds((const __attribute__((address_space(1))) u32*)g,
                                   (__attribute__((address_space(3))) u32*)l, 16, 0, 0);
}

// ---------------- prep kernels (coalesced) ----------------
__global__ void k_convx(const float4* __restrict__ x, u64* __restrict__ xb){
  long i = (long)blockIdx.x*blockDim.x + threadIdx.x;   // 8388608 threads
  float4 v = x[i];
  xb[i] = (u64)f2b(v.x) | ((u64)f2b(v.y)<<16) | ((u64)f2b(v.z)<<32) | ((u64)f2b(v.w)<<48);
}

// generic 64x64 LDS-tiled transpose f32 -> bf16 for WXT / PRJT / IPJT
__global__ __launch_bounds__(256)
void k_tr(const float* __restrict__ fw, const float* __restrict__ bw,
          const float* __restrict__ pw, const float* __restrict__ ipw,
          u16* __restrict__ wxt, u16* __restrict__ pjt, u16* __restrict__ ipjt){
  __shared__ u16 lds[64][66];
  const int b = blockIdx.x;                 // 3328 total
  const float* src; u16* dst; int srcLD, dstLD, r0, c0;
  if (b < 2304){                            // WXT: 6 mats x (16 k-tiles x 24 n-tiles)
    int mat = b / 384, tt = b % 384;
    int kt = tt % 16, nt = tt / 16;
    int d = mat / 3, l = mat % 3;
    src = (d ? bw : fw) + (size_t)l*1536*1536; srcLD = 1536;
    dst = wxt + (size_t)mat*1536*1024;        dstLD = 1024;
    r0 = kt*64; c0 = nt*64;
  } else if (b < 3072){                     // PRJT: 3 x (16x16)
    int bb = b - 2304, mat = bb / 256, tt = bb % 256;
    int kt = tt % 16, nt = tt / 16;
    src = pw + (size_t)mat*1048576; srcLD = 1024;
    dst = pjt + (size_t)mat*1048576; dstLD = 1024;
    r0 = kt*64; c0 = nt*64;
  } else {                                  // IPJT: 16x16
    int tt = b - 3072;
    int kt = tt % 16, nt = tt / 16;
    src = ipw; srcLD = 1024; dst = ipjt; dstLD = 1024;
    r0 = kt*64; c0 = nt*64;
  }
  const int tr = threadIdx.x >> 6, tc = threadIdx.x & 63;
  #pragma unroll
  for (int i=0;i<16;i++){
    int r = i*4 + tr;
    lds[r][tc] = f2b(src[(size_t)(r0+r)*srcLD + c0 + tc]);
  }
  __syncthreads();
  #pragma unroll
  for (int i=0;i<16;i++){
    int nr = i*4 + tr;
    dst[(size_t)(c0+nr)*dstLD + r0 + tc] = lds[tc][nr];
  }
}

// Wh fragment pack, coalesced reads via LDS tile
__global__ __launch_bounds__(256)
void k_whf2(const float* __restrict__ fw, const float* __restrict__ bw, u16* __restrict__ out){
  __shared__ u16 lds[64][66];
  const int b = blockIdx.x;                 // 1152 = 6 mats x (8 r-tiles x 24 c-tiles)
  const int mat = b / 192, tt = b % 192;
  const int rt = tt & 7, ct = tt >> 3;
  const int l = mat >> 1, d = mat & 1;
  const float* W = (d ? bw : fw) + (size_t)l*1536*1536;
  const int tr = threadIdx.x >> 6, tc = threadIdx.x & 63;
  #pragma unroll
  for (int i=0;i<16;i++){
    int r = i*4 + tr;
    lds[r][tc] = f2b(W[(size_t)(1024 + rt*64 + r)*1536 + ct*64 + tc]);
  }
  __syncthreads();
  const int t = threadIdx.x;
  const int lane = t >> 2;
  const int e0 = (t & 3)*2;
  u32* o32 = (u32*)out;
  #pragma unroll
  for (int kkl=0; kkl<2; ++kkl){
    int rl = kkl*32 + (lane>>4)*8 + e0;
    int kk = rt*2 + kkl;
    #pragma unroll
    for (int cg=0; cg<4; ++cg){
      int col = ct*64 + cg*16;
      int g = col >> 9;
      int wg = (col & 511) >> 4;
      size_t base16 = (size_t)l*1572864 + (size_t)((d*32+wg)*3 + g)*8192 + (size_t)kk*512;
      u16 lo = lds[rl    ][cg*16 + (lane&15)];
      u16 hi = lds[rl + 1][cg*16 + (lane&15)];
      o32[base16/2 + t] = (u32)lo | ((u32)hi<<16);
    }
  }
}

// ---------------- tiled bf16 MFMA GEMM (B^T input), fused epilogues ----------------
// round-8 exact (mblk-fastest mapping, plain stores).
template<int V>
__global__ __launch_bounds__(256)
void gemm_bt(const u16* __restrict__ A, const u16* __restrict__ Bt,
             const float* __restrict__ bias, int K,
             u16* __restrict__ Gout, int dir,
             float* __restrict__ inputs,
             const u16* __restrict__ ocat, u16* __restrict__ xbout,
             float* __restrict__ dout)
{
  __shared__ u16 As[128*64];
  __shared__ u16 Bs[128*64];
  const int tid = threadIdx.x, wid = tid>>6, lane = tid&63;
  const int wr = wid>>1, wc = wid&1;
  const int mblk = blockIdx.x & 255;
  const int nblk = blockIdx.x >> 8;
  f32x4 acc[4][4];
  #pragma unroll
  for (int i=0;i<4;i++)
    #pragma unroll
    for (int j=0;j<4;j++) acc[i][j] = (f32x4){0.f,0.f,0.f,0.f};
  const size_t Kb = (size_t)K*2;
  const char* Ab = (const char*)A + (size_t)(mblk*128)*Kb;
  const char* Bb = (const char*)Bt + (size_t)(nblk*128)*Kb;
  const int r8 = lane>>3, c8 = lane&7;
  for (int kt=0; kt<K/64; ++kt){
    __syncthreads();
    #pragma unroll
    for (int i=0;i<4;i++){
      const int instr = wid*4 + i;
      const int row = instr*8 + r8;
      const int so = (c8*16) ^ ((row&7)<<4);          // T2 swizzle via pre-swizzled src
      gl_lds16(Ab + (size_t)row*Kb + kt*128 + so, (char*)As + instr*1024);
      gl_lds16(Bb + (size_t)row*Kb + kt*128 + so, (char*)Bs + instr*1024);
    }
    __syncthreads();
    #pragma unroll
    for (int ks=0; ks<2; ++ks){
      bf16x8 af[4], bfv[4];
      #pragma unroll
      for (int mt=0;mt<4;mt++){
        int r = wr*64 + mt*16 + (lane&15);
        int kb = (ks*64 + ((lane>>4)*16)) ^ ((r&7)<<4);
        af[mt] = *(const bf16x8*)((const char*)As + r*128 + kb);
      }
      #pragma unroll
      for (int nt=0;nt<4;nt++){
        int r = wc*64 + nt*16 + (lane&15);
        int kb = (ks*64 + ((lane>>4)*16)) ^ ((r&7)<<4);
        bfv[nt] = *(const bf16x8*)((const char*)Bs + r*128 + kb);
      }
      #pragma unroll
      for (int mt=0;mt<4;mt++)
        #pragma unroll
        for (int nt=0;nt<4;nt++)
          acc[mt][nt] = __builtin_amdgcn_mfma_f32_16x16x32_bf16(af[mt], bfv[nt], acc[mt][nt], 0,0,0);
    }
  }
  const int mb = mblk*128 + wr*64;
  const int nb = nblk*128 + wc*64;
  #pragma unroll
  for (int nt=0;nt<4;nt++){
    const int n = nb + nt*16 + (lane&15);
    const float bv = bias[n];
    #pragma unroll
    for (int mt=0;mt<4;mt++){
      #pragma unroll
      for (int r=0;r<4;r++){
        const int m = mb + mt*16 + (lane>>4)*4 + r;
        float v = acc[mt][nt][r] + bv;
        if (V==0){
          int b = m >> 9, t = m & 511;
          int tp = dir ? (511 - t) : t;
          int brow = b & 15;
          size_t idx = (((size_t)tp*96 + (n>>9)*32 + ((n&511)>>4))*4 + (b>>4))*256
                     + ((brow>>2)<<6) + ((n&15)<<2) + (brow&3);
          Gout[idx] = f2b(v);
        } else if (V==1){
          inputs[(size_t)m*1024 + n] = v;
        } else {
          float g = sigm(v);
          size_t a = (size_t)m*1024 + n;
          float o = b2f((u32)ocat[a]);
          float nv = g*o + (1.f-g)*inputs[a];
          if (dout) dout[a] = nv;
          else { inputs[a] = nv; xbout[a] = f2b(nv); }
        }
      }
    }
  }
}

// ---------------- persistent recurrent kernel (round-17: combined poll) ----------
// grid = 128 blocks x 512 threads: (dir d, batch-slice bi of 16 rows, col-slice
// ci of 32 h-cols). Sync: per-producer monotone step-stamp flags; COMBINED
// parallel poll of both producers (one LLC latency), compiler barrier, THEN
// slice loads. This is the best-known configuration (5.80 ms).
__global__ __launch_bounds__(512, 1)
void lstm_rec(const u16* __restrict__ Whf, const u16* __restrict__ G,
              u16* __restrict__ hb,
              const float* __restrict__ h0f_, const float* __restrict__ c0f_,
              const float* __restrict__ h0b_, const float* __restrict__ c0b_,
              u16* __restrict__ ocat, u32* __restrict__ ctr, int lay)
{
  const int blk = blockIdx.x;
  const int d  = blk >> 6;
  const int bi = (blk >> 4) & 3;
  const int ci = blk & 15;
  const int tid = threadIdx.x;
  const int wave = tid >> 6, lane = tid & 63;

  __shared__ u16 hlds[16*544];          // logical [16][512], row stride 1088B, XOR-swz
  __shared__ float ldsg[3][16][37];
  __shared__ float ldsc[16][37];

  const int g = wave >> 1, half = wave & 1;
  const bool isg = (wave < 6);

  bf16x8 w[16];
  if (isg){
    const int wgg = ci*2 + half;
    const u16* wb = Whf + (((size_t)(d*32+wgg)*3 + g)*1024 + (size_t)lane)*8;
    #pragma unroll
    for (int kk=0;kk<16;kk++) w[kk] = *(const bf16x8*)(wb + kk*512);
  }
  const float* h0 = d ? h0b_ : h0f_;
  const float* c0 = d ? c0b_ : c0f_;
  u16* hbd = hb + (size_t)d*65536;                    // [2 parity][64][512] bf16
  const u16* Gd = G + (size_t)d*50331648ull;
  u32* av = ctr + (size_t)(d*4+bi)*512;               // group: 16 slots x 32 u32
  const u32 labase = (u32)lay * 513u;

  // init h(0) slice + c0
  if (tid < 256){
    int b = tid >> 4, c2 = (tid & 15)*2;
    int col = ci*32 + c2;
    u32 pk = (u32)f2b(h0[col]) | ((u32)f2b(h0[col+1])<<16);
    __hip_atomic_store((u32*)(hbd + (size_t)(bi*16+b)*512 + col), pk,
                       __ATOMIC_RELAXED, __HIP_MEMORY_SCOPE_AGENT);
    ldsc[b][c2]   = c0[col];
    ldsc[b][c2+1] = c0[col+1];
  }
  __syncthreads();                       // drains init stores
  if (tid==0)
    __hip_atomic_store(av + ci*32, labase + 1u, __ATOMIC_RELAXED, __HIP_MEMORY_SCOPE_AGENT);

  const int ntile = g*32 + ci*2 + half;
  s16x4 q{};
  if (isg)
    q = *(const s16x4*)(Gd + (((size_t)0*96 + ntile)*4 + bi)*256 + lane*4);

  const int srow = lane >> 2;            // staging: row 0..15
  const int part = lane & 3;             // 16B chunk within a producer slice
  const int p0 = wave*2, p1 = wave*2 + 1;
  const int swzw = (srow & 7) << 4;
  char* hlrow = (char*)hlds + srow*1088;
  const int mr = lane & 15;              // MFMA A row
  const char* ab = (const char*)hlds + mr*1088;
  const int c16 = (lane>>4)*16;
  const int swzr = (mr & 7) << 4;

  for (int t=0; t<512; ++t){
    // ---- combined parallel poll of both producers, barrier, THEN stage ----
    const u32 tgt = labase + (u32)t + 1u;
    const u64* hsrc = (const u64*)(hbd + (size_t)(t&1)*32768) + (size_t)bi*2048;
    for (;;){
      u32 fa = __hip_atomic_load(av + p0*32, __ATOMIC_RELAXED, __HIP_MEMORY_SCOPE_AGENT);
      u32 fb = __hip_atomic_load(av + p1*32, __ATOMIC_RELAXED, __HIP_MEMORY_SCOPE_AGENT);
      if (fa >= tgt && fb >= tgt) break;
    }
    asm volatile("" ::: "memory");      // forbid hoisting the slice loads above the polls
    u64 a0 = __hip_atomic_load(hsrc + srow*128 + p0*8 + part*2,     __ATOMIC_RELAXED, __HIP_MEMORY_SCOPE_AGENT);
    u64 a1 = __hip_atomic_load(hsrc + srow*128 + p0*8 + part*2 + 1, __ATOMIC_RELAXED, __HIP_MEMORY_SCOPE_AGENT);
    u64 b0 = __hip_atomic_load(hsrc + srow*128 + p1*8 + part*2,     __ATOMIC_RELAXED, __HIP_MEMORY_SCOPE_AGENT);
    u64 b1 = __hip_atomic_load(hsrc + srow*128 + p1*8 + part*2 + 1, __ATOMIC_RELAXED, __HIP_MEMORY_SCOPE_AGENT);
    *(u64*)(hlrow + ((p0*64 + part*16) ^ swzw))     = a0;
    *(u64*)(hlrow + ((p0*64 + part*16) ^ swzw) + 8) = a1;
    *(u64*)(hlrow + ((p1*64 + part*16) ^ swzw))     = b0;
    *(u64*)(hlrow + ((p1*64 + part*16) ^ swzw) + 8) = b1;
    __syncthreads();

    if (isg){
      f32x4 ea={0.f,0.f,0.f,0.f}, eb={0.f,0.f,0.f,0.f};
      #pragma unroll
      for (int kk=0;kk<16;kk+=2){
        bf16x8 a0v = *(const bf16x8*)(ab + ((kk*64     + c16) ^ swzr));
        bf16x8 a1v = *(const bf16x8*)(ab + ((kk*64+64  + c16) ^ swzr));
        ea = __builtin_amdgcn_mfma_f32_16x16x32_bf16(a0v, w[kk],   ea, 0,0,0);
        eb = __builtin_amdgcn_mfma_f32_16x16x32_bf16(a1v, w[kk+1], eb, 0,0,0);
      }
      const int bb = (lane>>4)*4;
      const int cc = half*16 + (lane&15);
      #pragma unroll
      for (int r=0;r<4;r++)
        ldsg[g][bb+r][cc] = ea[r] + eb[r] + b2f((u32)(u16)q[r]);
    }
    __syncthreads();

    // ---- cell update + write h(t+1) (agent), ocat (plain) ----
    const int t_o = d ? (511 - t) : t;
    u16* hnxt = hbd + (size_t)((t+1)&1)*32768;
    if (tid < 256){
      int b = tid>>4, c2 = (tid&15)*2;
      float i0 = sigm(ldsg[0][b][c2]);
      float i1 = sigm(ldsg[0][b][c2+1]);
      float cn0 = (1.f-i0)*ldsc[b][c2]   + i0*tanh_f(ldsg[1][b][c2]);
      float cn1 = (1.f-i1)*ldsc[b][c2+1] + i1*tanh_f(ldsg[1][b][c2+1]);
      ldsc[b][c2] = cn0; ldsc[b][c2+1] = cn1;
      float hv0 = tanh_f(cn0)*sigm(ldsg[2][b][c2]);
      float hv1 = tanh_f(cn1)*sigm(ldsg[2][b][c2+1]);
      u32 pk = (u32)f2b(hv0) | ((u32)f2b(hv1)<<16);
      int gb = bi*16 + b, col = ci*32 + c2;
      __hip_atomic_store((u32*)(hnxt + (size_t)gb*512 + col), pk,
                         __ATOMIC_RELAXED, __HIP_MEMORY_SCOPE_AGENT);
      *(u32*)(ocat + (((size_t)(gb*512 + t_o))<<10) + (d<<9) + col) = pk;
    }
    __syncthreads();                     // all stores drained (per-wave vmcnt + barrier)

    if (tid==0)
      __hip_atomic_store(av + ci*32, labase + (u32)t + 2u,
                         __ATOMIC_RELAXED, __HIP_MEMORY_SCOPE_AGENT);
    if (isg){
      int tn = (t+1 < 512) ? (t+1) : 511;
      q = *(const s16x4*)(Gd + (((size_t)tn*96 + ntile)*4 + bi)*256 + lane*4);
    }
  }
}

extern "C" void kernel_launch(void* const* d_in, const int* in_sizes, int n_in,
                              void* d_out, int out_size, void* d_ws, size_t ws_size,
                              hipStream_t stream)
{
  (void)in_sizes; (void)n_in; (void)out_size;
  if (ws_size < WS_NEED) return;
  const float* x      = (const float*)d_in[0];
  const float* fw_W   = (const float*)d_in[1];
  const float* fw_b   = (const float*)d_in[2];
  const float* bw_W   = (const float*)d_in[3];
  const float* bw_b   = (const float*)d_in[4];
  const float* h0f    = (const float*)d_in[5];
  const float* c0f    = (const float*)d_in[6];
  const float* h0b    = (const float*)d_in[7];
  const float* c0b    = (const float*)d_in[8];
  const float* proj_W = (const float*)d_in[9];
  const float* proj_b = (const float*)d_in[10];
  const float* ipW    = (const float*)d_in[11];
  const float* ipb    = (const float*)d_in[12];
  char* ws = (char*)d_ws;
  u16* WXT  = (u16*)(ws + OFF_WXT);
  u16* WHF  = (u16*)(ws + OFF_WHF);
  u16* PRJT = (u16*)(ws + OFF_PRJT);
  u16* IPJT = (u16*)(ws + OFF_IPJT);
  u16* XB   = (u16*)(ws + OFF_XB);
  u16* GB   = (u16*)(ws + OFF_G);
  u16* OCAT = (u16*)(ws + OFF_OCAT);
  float* INP= (float*)(ws + OFF_INP);
  u16* HB   = (u16*)(ws + OFF_HB);
  u32* CTR  = (u32*)(ws + OFF_CTR);

  hipMemsetAsync(CTR, 0, 16384, stream);
  k_convx<<<32768, 256, 0, stream>>>((const float4*)x, (u64*)XB);
  k_tr<<<3328, 256, 0, stream>>>(fw_W, bw_W, proj_W, ipW, WXT, PRJT, IPJT);
  k_whf2<<<1152, 256, 0, stream>>>(fw_W, bw_W, WHF);

  gemm_bt<1><<<2048, 256, 0, stream>>>(XB, IPJT, ipb, 1024, nullptr, 0, INP, nullptr, nullptr, nullptr);

  for (int l=0; l<3; ++l){
    gemm_bt<0><<<3072, 256, 0, stream>>>(XB, WXT + (size_t)l*1572864, fw_b + l*1536, 1024,
                                         GB, 0, nullptr, nullptr, nullptr, nullptr);
    gemm_bt<0><<<3072, 256, 0, stream>>>(XB, WXT + (size_t)(3+l)*1572864, bw_b + l*1536, 1024,
                                         GB + 50331648ull, 1, nullptr, nullptr, nullptr, nullptr);
    {
      const u16* whfl = WHF + (size_t)l*1572864;
      const u16* gbp  = GB;
      u16* hbp = HB;
      const float* p1 = h0f + l*512;
      const float* p2 = c0f + l*512;
      const float* p3 = h0b + l*512;
      const float* p4 = c0b + l*512;
      u16* ocp = OCAT;
      u32* ctp = CTR;
      int lay = l;
      void* args[] = { (void*)&whfl, (void*)&gbp, (void*)&hbp,
                       (void*)&p1, (void*)&p2, (void*)&p3, (void*)&p4,
                       (void*)&ocp, (void*)&ctp, (void*)&lay };
      hipLaunchCooperativeKernel((void*)lstm_rec, dim3(128), dim3(512), args, 0, stream);
    }
    gemm_bt<2><<<2048, 256, 0, stream>>>(OCAT, PRJT + (size_t)l*1048576, proj_b + l*1024, 1024,
                                         nullptr, 0, INP, OCAT, XB,
                                         (l==2) ? (float*)d_out : nullptr);
  }
}

// Round 20
// 5722.126 us; speedup vs baseline: 1.0844x; 1.0237x over previous
//
#include <hip/hip_runtime.h>
#include <stdint.h>

typedef short bf16x8 __attribute__((ext_vector_type(8)));
typedef short s16x4 __attribute__((ext_vector_type(4)));
typedef float f32x4 __attribute__((ext_vector_type(4)));
typedef unsigned int u32;
typedef unsigned short u16;
typedef unsigned long long u64;

// ---------------- workspace layout (bytes) ----------------
#define OFF_WXT  0ull                  // [2][3][1536][1024] bf16  (Wx transposed)
#define OFF_WHF  18874368ull           // [3][2][32][3][16][64][8] bf16 (Wh frags)
#define OFF_CTR  28311552ull           // [8 groups][16 producers] flag lines (128B)
#define OFF_PRJT 37748736ull           // [3][1024][1024] bf16 (proj_W^T)
#define OFF_IPJT 44040192ull           // [1024][1024] bf16 (in_proj_W^T)
#define OFF_XB   46137344ull           // [32768][1024] bf16 (activations)
#define OFF_G    113246208ull          // [2][512*96*4][256] bf16 (gate-x frags)
#define OFF_OCAT 314572800ull          // [32768][1024] bf16 (hf|hb)
#define OFF_INP  381681664ull          // [32768][1024] f32 (highway inputs)
#define OFF_HB   515899392ull          // [2][2][64][512] bf16 (h double-buf)
#define WS_NEED  516161536ull

__device__ __forceinline__ float b2f(u32 u){ return __uint_as_float(u<<16); }
__device__ __forceinline__ u16 f2b(float f){
  u32 i = __float_as_uint(f);
  return (u16)((i + 0x7FFFu + ((i>>16)&1u))>>16);
}
__device__ __forceinline__ float sigm(float x){ return 1.f/(1.f+__expf(-x)); }
__device__ __forceinline__ float tanh_f(float x){
  x = fminf(fmaxf(x,-15.f),15.f);
  float e = __expf(2.f*x);
  return (e-1.f)/(e+1.f);
}
__device__ __forceinline__ void gl_lds16(const void* g, void* l){
  __builtin_amdgcn_global_load_lds((const __attribute__((address_space(1))) u32*)g,
                                   (__attribute__((address_space(3))) u32*)l, 16, 0, 0);
}

// ---------------- prep kernels (coalesced) ----------------
__global__ void k_convx(const float4* __restrict__ x, u64* __restrict__ xb){
  long i = (long)blockIdx.x*blockDim.x + threadIdx.x;   // 8388608 threads
  float4 v = x[i];
  xb[i] = (u64)f2b(v.x) | ((u64)f2b(v.y)<<16) | ((u64)f2b(v.z)<<32) | ((u64)f2b(v.w)<<48);
}

// generic 64x64 LDS-tiled transpose f32 -> bf16 for WXT / PRJT / IPJT
__global__ __launch_bounds__(256)
void k_tr(const float* __restrict__ fw, const float* __restrict__ bw,
          const float* __restrict__ pw, const float* __restrict__ ipw,
          u16* __restrict__ wxt, u16* __restrict__ pjt, u16* __restrict__ ipjt){
  __shared__ u16 lds[64][66];
  const int b = blockIdx.x;                 // 3328 total
  const float* src; u16* dst; int srcLD, dstLD, r0, c0;
  if (b < 2304){                            // WXT: 6 mats x (16 k-tiles x 24 n-tiles)
    int mat = b / 384, tt = b % 384;
    int kt = tt % 16, nt = tt / 16;
    int d = mat / 3, l = mat % 3;
    src = (d ? bw : fw) + (size_t)l*1536*1536; srcLD = 1536;
    dst = wxt + (size_t)mat*1536*1024;        dstLD = 1024;
    r0 = kt*64; c0 = nt*64;
  } else if (b < 3072){                     // PRJT: 3 x (16x16)
    int bb = b - 2304, mat = bb / 256, tt = bb % 256;
    int kt = tt % 16, nt = tt / 16;
    src = pw + (size_t)mat*1048576; srcLD = 1024;
    dst = pjt + (size_t)mat*1048576; dstLD = 1024;
    r0 = kt*64; c0 = nt*64;
  } else {                                  // IPJT: 16x16
    int tt = b - 3072;
    int kt = tt % 16, nt = tt / 16;
    src = ipw; srcLD = 1024; dst = ipjt; dstLD = 1024;
    r0 = kt*64; c0 = nt*64;
  }
  const int tr = threadIdx.x >> 6, tc = threadIdx.x & 63;
  #pragma unroll
  for (int i=0;i<16;i++){
    int r = i*4 + tr;
    lds[r][tc] = f2b(src[(size_t)(r0+r)*srcLD + c0 + tc]);
  }
  __syncthreads();
  #pragma unroll
  for (int i=0;i<16;i++){
    int nr = i*4 + tr;
    dst[(size_t)(c0+nr)*dstLD + r0 + tc] = lds[tc][nr];
  }
}

// Wh fragment pack, coalesced reads via LDS tile
__global__ __launch_bounds__(256)
void k_whf2(const float* __restrict__ fw, const float* __restrict__ bw, u16* __restrict__ out){
  __shared__ u16 lds[64][66];
  const int b = blockIdx.x;                 // 1152 = 6 mats x (8 r-tiles x 24 c-tiles)
  const int mat = b / 192, tt = b % 192;
  const int rt = tt & 7, ct = tt >> 3;
  const int l = mat >> 1, d = mat & 1;
  const float* W = (d ? bw : fw) + (size_t)l*1536*1536;
  const int tr = threadIdx.x >> 6, tc = threadIdx.x & 63;
  #pragma unroll
  for (int i=0;i<16;i++){
    int r = i*4 + tr;
    lds[r][tc] = f2b(W[(size_t)(1024 + rt*64 + r)*1536 + ct*64 + tc]);
  }
  __syncthreads();
  const int t = threadIdx.x;
  const int lane = t >> 2;
  const int e0 = (t & 3)*2;
  u32* o32 = (u32*)out;
  #pragma unroll
  for (int kkl=0; kkl<2; ++kkl){
    int rl = kkl*32 + (lane>>4)*8 + e0;
    int kk = rt*2 + kkl;
    #pragma unroll
    for (int cg=0; cg<4; ++cg){
      int col = ct*64 + cg*16;
      int g = col >> 9;
      int wg = (col & 511) >> 4;
      size_t base16 = (size_t)l*1572864 + (size_t)((d*32+wg)*3 + g)*8192 + (size_t)kk*512;
      u16 lo = lds[rl    ][cg*16 + (lane&15)];
      u16 hi = lds[rl + 1][cg*16 + (lane&15)];
      o32[base16/2 + t] = (u32)lo | ((u32)hi<<16);
    }
  }
}

// ---------------- tiled bf16 MFMA GEMM (B^T input), fused epilogues ----------------
// round-8 exact (mblk-fastest mapping, plain stores).
template<int V>
__global__ __launch_bounds__(256)
void gemm_bt(const u16* __restrict__ A, const u16* __restrict__ Bt,
             const float* __restrict__ bias, int K,
             u16* __restrict__ Gout, int dir,
             float* __restrict__ inputs,
             const u16* __restrict__ ocat, u16* __restrict__ xbout,
             float* __restrict__ dout)
{
  __shared__ u16 As[128*64];
  __shared__ u16 Bs[128*64];
  const int tid = threadIdx.x, wid = tid>>6, lane = tid&63;
  const int wr = wid>>1, wc = wid&1;
  const int mblk = blockIdx.x & 255;
  const int nblk = blockIdx.x >> 8;
  f32x4 acc[4][4];
  #pragma unroll
  for (int i=0;i<4;i++)
    #pragma unroll
    for (int j=0;j<4;j++) acc[i][j] = (f32x4){0.f,0.f,0.f,0.f};
  const size_t Kb = (size_t)K*2;
  const char* Ab = (const char*)A + (size_t)(mblk*128)*Kb;
  const char* Bb = (const char*)Bt + (size_t)(nblk*128)*Kb;
  const int r8 = lane>>3, c8 = lane&7;
  for (int kt=0; kt<K/64; ++kt){
    __syncthreads();
    #pragma unroll
    for (int i=0;i<4;i++){
      const int instr = wid*4 + i;
      const int row = instr*8 + r8;
      const int so = (c8*16) ^ ((row&7)<<4);          // T2 swizzle via pre-swizzled src
      gl_lds16(Ab + (size_t)row*Kb + kt*128 + so, (char*)As + instr*1024);
      gl_lds16(Bb + (size_t)row*Kb + kt*128 + so, (char*)Bs + instr*1024);
    }
    __syncthreads();
    #pragma unroll
    for (int ks=0; ks<2; ++ks){
      bf16x8 af[4], bfv[4];
      #pragma unroll
      for (int mt=0;mt<4;mt++){
        int r = wr*64 + mt*16 + (lane&15);
        int kb = (ks*64 + ((lane>>4)*16)) ^ ((r&7)<<4);
        af[mt] = *(const bf16x8*)((const char*)As + r*128 + kb);
      }
      #pragma unroll
      for (int nt=0;nt<4;nt++){
        int r = wc*64 + nt*16 + (lane&15);
        int kb = (ks*64 + ((lane>>4)*16)) ^ ((r&7)<<4);
        bfv[nt] = *(const bf16x8*)((const char*)Bs + r*128 + kb);
      }
      #pragma unroll
      for (int mt=0;mt<4;mt++)
        #pragma unroll
        for (int nt=0;nt<4;nt++)
          acc[mt][nt] = __builtin_amdgcn_mfma_f32_16x16x32_bf16(af[mt], bfv[nt], acc[mt][nt], 0,0,0);
    }
  }
  const int mb = mblk*128 + wr*64;
  const int nb = nblk*128 + wc*64;
  #pragma unroll
  for (int nt=0;nt<4;nt++){
    const int n = nb + nt*16 + (lane&15);
    const float bv = bias[n];
    #pragma unroll
    for (int mt=0;mt<4;mt++){
      #pragma unroll
      for (int r=0;r<4;r++){
        const int m = mb + mt*16 + (lane>>4)*4 + r;
        float v = acc[mt][nt][r] + bv;
        if (V==0){
          int b = m >> 9, t = m & 511;
          int tp = dir ? (511 - t) : t;
          int brow = b & 15;
          size_t idx = (((size_t)tp*96 + (n>>9)*32 + ((n&511)>>4))*4 + (b>>4))*256
                     + ((brow>>2)<<6) + ((n&15)<<2) + (brow&3);
          Gout[idx] = f2b(v);
        } else if (V==1){
          inputs[(size_t)m*1024 + n] = v;
        } else {
          float g = sigm(v);
          size_t a = (size_t)m*1024 + n;
          float o = b2f((u32)ocat[a]);
          float nv = g*o + (1.f-g)*inputs[a];
          if (dout) dout[a] = nv;
          else { inputs[a] = nv; xbout[a] = f2b(nv); }
        }
      }
    }
  }
}

// ---------------- persistent recurrent kernel ----------------
// grid = 128 blocks x 512 threads: (dir d, batch-slice bi of 16 rows, col-slice
// ci of 32 h-cols). Round-17 combined poll retained.
// ROUND 20 (only delta): ocat stores moved AFTER the flag store -- they are
// consumed only by the proj GEMM post-kernel, so they don't belong in the
// pre-signal vmcnt drain (scattered 2KB-stride stores, 64 lines/wave). The
// h stores alone are drained by the barrier before the flag; ocat stores
// overlap the next step's poll and retire long before the post-staging barrier.
__global__ __launch_bounds__(512, 1)
void lstm_rec(const u16* __restrict__ Whf, const u16* __restrict__ G,
              u16* __restrict__ hb,
              const float* __restrict__ h0f_, const float* __restrict__ c0f_,
              const float* __restrict__ h0b_, const float* __restrict__ c0b_,
              u16* __restrict__ ocat, u32* __restrict__ ctr, int lay)
{
  const int blk = blockIdx.x;
  const int d  = blk >> 6;
  const int bi = (blk >> 4) & 3;
  const int ci = blk & 15;
  const int tid = threadIdx.x;
  const int wave = tid >> 6, lane = tid & 63;

  __shared__ u16 hlds[16*544];          // logical [16][512], row stride 1088B, XOR-swz
  __shared__ float ldsg[3][16][37];
  __shared__ float ldsc[16][37];

  const int g = wave >> 1, half = wave & 1;
  const bool isg = (wave < 6);

  bf16x8 w[16];
  if (isg){
    const int wgg = ci*2 + half;
    const u16* wb = Whf + (((size_t)(d*32+wgg)*3 + g)*1024 + (size_t)lane)*8;
    #pragma unroll
    for (int kk=0;kk<16;kk++) w[kk] = *(const bf16x8*)(wb + kk*512);
  }
  const float* h0 = d ? h0b_ : h0f_;
  const float* c0 = d ? c0b_ : c0f_;
  u16* hbd = hb + (size_t)d*65536;                    // [2 parity][64][512] bf16
  const u16* Gd = G + (size_t)d*50331648ull;
  u32* av = ctr + (size_t)(d*4+bi)*512;               // group: 16 slots x 32 u32
  const u32 labase = (u32)lay * 513u;

  // init h(0) slice + c0
  if (tid < 256){
    int b = tid >> 4, c2 = (tid & 15)*2;
    int col = ci*32 + c2;
    u32 pk = (u32)f2b(h0[col]) | ((u32)f2b(h0[col+1])<<16);
    __hip_atomic_store((u32*)(hbd + (size_t)(bi*16+b)*512 + col), pk,
                       __ATOMIC_RELAXED, __HIP_MEMORY_SCOPE_AGENT);
    ldsc[b][c2]   = c0[col];
    ldsc[b][c2+1] = c0[col+1];
  }
  __syncthreads();                       // drains init stores
  if (tid==0)
    __hip_atomic_store(av + ci*32, labase + 1u, __ATOMIC_RELAXED, __HIP_MEMORY_SCOPE_AGENT);

  const int ntile = g*32 + ci*2 + half;
  s16x4 q{};
  if (isg)
    q = *(const s16x4*)(Gd + (((size_t)0*96 + ntile)*4 + bi)*256 + lane*4);

  const int srow = lane >> 2;            // staging: row 0..15
  const int part = lane & 3;             // 16B chunk within a producer slice
  const int p0 = wave*2, p1 = wave*2 + 1;
  const int swzw = (srow & 7) << 4;
  char* hlrow = (char*)hlds + srow*1088;
  const int mr = lane & 15;              // MFMA A row
  const char* ab = (const char*)hlds + mr*1088;
  const int c16 = (lane>>4)*16;
  const int swzr = (mr & 7) << 4;

  for (int t=0; t<512; ++t){
    // ---- combined parallel poll of both producers, barrier, THEN stage ----
    const u32 tgt = labase + (u32)t + 1u;
    const u64* hsrc = (const u64*)(hbd + (size_t)(t&1)*32768) + (size_t)bi*2048;
    for (;;){
      u32 fa = __hip_atomic_load(av + p0*32, __ATOMIC_RELAXED, __HIP_MEMORY_SCOPE_AGENT);
      u32 fb = __hip_atomic_load(av + p1*32, __ATOMIC_RELAXED, __HIP_MEMORY_SCOPE_AGENT);
      if (fa >= tgt && fb >= tgt) break;
    }
    asm volatile("" ::: "memory");      // forbid hoisting the slice loads above the polls
    u64 a0 = __hip_atomic_load(hsrc + srow*128 + p0*8 + part*2,     __ATOMIC_RELAXED, __HIP_MEMORY_SCOPE_AGENT);
    u64 a1 = __hip_atomic_load(hsrc + srow*128 + p0*8 + part*2 + 1, __ATOMIC_RELAXED, __HIP_MEMORY_SCOPE_AGENT);
    u64 b0 = __hip_atomic_load(hsrc + srow*128 + p1*8 + part*2,     __ATOMIC_RELAXED, __HIP_MEMORY_SCOPE_AGENT);
    u64 b1 = __hip_atomic_load(hsrc + srow*128 + p1*8 + part*2 + 1, __ATOMIC_RELAXED, __HIP_MEMORY_SCOPE_AGENT);
    *(u64*)(hlrow + ((p0*64 + part*16) ^ swzw))     = a0;
    *(u64*)(hlrow + ((p0*64 + part*16) ^ swzw) + 8) = a1;
    *(u64*)(hlrow + ((p1*64 + part*16) ^ swzw))     = b0;
    *(u64*)(hlrow + ((p1*64 + part*16) ^ swzw) + 8) = b1;
    __syncthreads();

    if (isg){
      f32x4 ea={0.f,0.f,0.f,0.f}, eb={0.f,0.f,0.f,0.f};
      #pragma unroll
      for (int kk=0;kk<16;kk+=2){
        bf16x8 a0v = *(const bf16x8*)(ab + ((kk*64     + c16) ^ swzr));
        bf16x8 a1v = *(const bf16x8*)(ab + ((kk*64+64  + c16) ^ swzr));
        ea = __builtin_amdgcn_mfma_f32_16x16x32_bf16(a0v, w[kk],   ea, 0,0,0);
        eb = __builtin_amdgcn_mfma_f32_16x16x32_bf16(a1v, w[kk+1], eb, 0,0,0);
      }
      const int bb = (lane>>4)*4;
      const int cc = half*16 + (lane&15);
      #pragma unroll
      for (int r=0;r<4;r++)
        ldsg[g][bb+r][cc] = ea[r] + eb[r] + b2f((u32)(u16)q[r]);
    }
    __syncthreads();

    // ---- cell update: h store ONLY before the signal ----
    u16* hnxt = hbd + (size_t)((t+1)&1)*32768;
    u32 pk = 0;
    if (tid < 256){
      int b = tid>>4, c2 = (tid&15)*2;
      float i0 = sigm(ldsg[0][b][c2]);
      float i1 = sigm(ldsg[0][b][c2+1]);
      float cn0 = (1.f-i0)*ldsc[b][c2]   + i0*tanh_f(ldsg[1][b][c2]);
      float cn1 = (1.f-i1)*ldsc[b][c2+1] + i1*tanh_f(ldsg[1][b][c2+1]);
      ldsc[b][c2] = cn0; ldsc[b][c2+1] = cn1;
      float hv0 = tanh_f(cn0)*sigm(ldsg[2][b][c2]);
      float hv1 = tanh_f(cn1)*sigm(ldsg[2][b][c2+1]);
      pk = (u32)f2b(hv0) | ((u32)f2b(hv1)<<16);
      int gb = bi*16 + b, col = ci*32 + c2;
      __hip_atomic_store((u32*)(hnxt + (size_t)gb*512 + col), pk,
                         __ATOMIC_RELAXED, __HIP_MEMORY_SCOPE_AGENT);
    }
    __syncthreads();                     // drains h stores (per-wave vmcnt + barrier)

    if (tid==0)
      __hip_atomic_store(av + ci*32, labase + (u32)t + 2u,
                         __ATOMIC_RELAXED, __HIP_MEMORY_SCOPE_AGENT);

    // ---- deferred ocat write (off the signal path; overlaps next poll) ----
    if (tid < 256){
      int b = tid>>4, c2 = (tid&15)*2;
      int t_o = d ? (511 - t) : t;
      int gb = bi*16 + b, col = ci*32 + c2;
      *(u32*)(ocat + (((size_t)(gb*512 + t_o))<<10) + (d<<9) + col) = pk;
    }
    if (isg){
      int tn = (t+1 < 512) ? (t+1) : 511;
      q = *(const s16x4*)(Gd + (((size_t)tn*96 + ntile)*4 + bi)*256 + lane*4);
    }
  }
}

extern "C" void kernel_launch(void* const* d_in, const int* in_sizes, int n_in,
                              void* d_out, int out_size, void* d_ws, size_t ws_size,
                              hipStream_t stream)
{
  (void)in_sizes; (void)n_in; (void)out_size;
  if (ws_size < WS_NEED) return;
  const float* x      = (const float*)d_in[0];
  const float* fw_W   = (const float*)d_in[1];
  const float* fw_b   = (const float*)d_in[2];
  const float* bw_W   = (const float*)d_in[3];
  const float* bw_b   = (const float*)d_in[4];
  const float* h0f    = (const float*)d_in[5];
  const float* c0f    = (const float*)d_in[6];
  const float* h0b    = (const float*)d_in[7];
  const float* c0b    = (const float*)d_in[8];
  const float* proj_W = (const float*)d_in[9];
  const float* proj_b = (const float*)d_in[10];
  const float* ipW    = (const float*)d_in[11];
  const float* ipb    = (const float*)d_in[12];
  char* ws = (char*)d_ws;
  u16* WXT  = (u16*)(ws + OFF_WXT);
  u16* WHF  = (u16*)(ws + OFF_WHF);
  u16* PRJT = (u16*)(ws + OFF_PRJT);
  u16* IPJT = (u16*)(ws + OFF_IPJT);
  u16* XB   = (u16*)(ws + OFF_XB);
  u16* GB   = (u16*)(ws + OFF_G);
  u16* OCAT = (u16*)(ws + OFF_OCAT);
  float* INP= (float*)(ws + OFF_INP);
  u16* HB   = (u16*)(ws + OFF_HB);
  u32* CTR  = (u32*)(ws + OFF_CTR);

  hipMemsetAsync(CTR, 0, 16384, stream);
  k_convx<<<32768, 256, 0, stream>>>((const float4*)x, (u64*)XB);
  k_tr<<<3328, 256, 0, stream>>>(fw_W, bw_W, proj_W, ipW, WXT, PRJT, IPJT);
  k_whf2<<<1152, 256, 0, stream>>>(fw_W, bw_W, WHF);

  gemm_bt<1><<<2048, 256, 0, stream>>>(XB, IPJT, ipb, 1024, nullptr, 0, INP, nullptr, nullptr, nullptr);

  for (int l=0; l<3; ++l){
    gemm_bt<0><<<3072, 256, 0, stream>>>(XB, WXT + (size_t)l*1572864, fw_b + l*1536, 1024,
                                         GB, 0, nullptr, nullptr, nullptr, nullptr);
    gemm_bt<0><<<3072, 256, 0, stream>>>(XB, WXT + (size_t)(3+l)*1572864, bw_b + l*1536, 1024,
                                         GB + 50331648ull, 1, nullptr, nullptr, nullptr, nullptr);
    {
      const u16* whfl = WHF + (size_t)l*1572864;
      const u16* gbp  = GB;
      u16* hbp = HB;
      const float* p1 = h0f + l*512;
      const float* p2 = c0f + l*512;
      const float* p3 = h0b + l*512;
      const float* p4 = c0b + l*512;
      u16* ocp = OCAT;
      u32* ctp = CTR;
      int lay = l;
      void* args[] = { (void*)&whfl, (void*)&gbp, (void*)&hbp,
                       (void*)&p1, (void*)&p2, (void*)&p3, (void*)&p4,
                       (void*)&ocp, (void*)&ctp, (void*)&lay };
      hipLaunchCooperativeKernel((void*)lstm_rec, dim3(128), dim3(512), args, 0, stream);
    }
    gemm_bt<2><<<2048, 256, 0, stream>>>(OCAT, PRJT + (size_t)l*1048576, proj_b + l*1024, 1024,
                                         nullptr, 0, INP, OCAT, XB,
                                         (l==2) ? (float*)d_out : nullptr);
  }
}